// Round 1
// baseline (1301.865 us; speedup 1.0000x reference)
//
#include <hip/hip_runtime.h>
#include <hip/hip_bf16.h>
#include <math.h>

// CrossEntropyWithPerDomainLoss on MI355X (gfx950)
// B=4, S=2048, V=32000, D=8. Memory-bound: single pass over 1.048 GB of logits.

#define NDOM 8

// ---------------- Kernel 1: per-token online-softmax CE loss ----------------
// One 256-thread block per token. float4 vector loads, online (m,s) update,
// wave shuffle reduce + 4-wave LDS combine.
__global__ __launch_bounds__(256) void ce_per_token_kernel(
    const float* __restrict__ logits,   // [T, V]
    const int* __restrict__ labels,     // [T]
    float* __restrict__ per_token_loss, // [T] (workspace)
    int V)                              // vocab, multiple of 4
{
    const int token = blockIdx.x;
    const int t = threadIdx.x;
    const float4* row = reinterpret_cast<const float4*>(logits + (size_t)token * (size_t)V);
    const int V4 = V >> 2;

    float m = -INFINITY;
    float s = 0.0f;

    for (int j = t; j < V4; j += 256) {
        float4 v = row[j];
        float m4 = fmaxf(fmaxf(v.x, v.y), fmaxf(v.z, v.w));
        float mn = fmaxf(m, m4);
        // exp(-inf) = 0 handles the first iteration (m = -inf) correctly
        s = s * __expf(m - mn)
          + __expf(v.x - mn) + __expf(v.y - mn)
          + __expf(v.z - mn) + __expf(v.w - mn);
        m = mn;
    }

    // 64-lane butterfly reduce of the (m, s) pair
    #pragma unroll
    for (int off = 1; off < 64; off <<= 1) {
        float mo = __shfl_xor(m, off, 64);
        float so = __shfl_xor(s, off, 64);
        float mn = fmaxf(m, mo);
        s = s * __expf(m - mn) + so * __expf(mo - mn);
        m = mn;
    }

    // combine the 4 waves via LDS
    __shared__ float sm[4];
    __shared__ float ss[4];
    const int wave = t >> 6;
    if ((t & 63) == 0) { sm[wave] = m; ss[wave] = s; }
    __syncthreads();

    if (t == 0) {
        float M = fmaxf(fmaxf(sm[0], sm[1]), fmaxf(sm[2], sm[3]));
        float S = ss[0] * __expf(sm[0] - M) + ss[1] * __expf(sm[1] - M)
                + ss[2] * __expf(sm[2] - M) + ss[3] * __expf(sm[3] - M);
        int lab = labels[token];
        float x = logits[(size_t)token * (size_t)V + (size_t)lab];
        per_token_loss[token] = M + __logf(S) - x;  // lse - logit[label]
    }
}

// ---------------- Kernel 2: reductions + per-domain finalize ----------------
// Single 256-thread block. T = B*S = 8192 tiny floats — negligible cost.
__global__ __launch_bounds__(256) void ce_finalize_kernel(
    const float* __restrict__ per_token_loss, // [T]
    const int* __restrict__ mask,             // [T] (bool as int)
    const int* __restrict__ domain_idxs,      // [B]
    float* __restrict__ out,                  // [1 + NDOM + NDOM]
    int T, int B, int S)
{
    const int t = threadIdx.x;
    float tot = 0.0f, cnt = 0.0f;
    float samp[4] = {0.f, 0.f, 0.f, 0.f};  // B == 4

    for (int i = t; i < T; i += 256) {
        float l = per_token_loss[i];
        if (mask[i] != 0) { tot += l; cnt += 1.0f; }
        samp[i / S] += l;  // per-sample sums are UNMASKED in the reference
    }

    __shared__ float red[6][256];
    red[0][t] = tot;     red[1][t] = cnt;
    red[2][t] = samp[0]; red[3][t] = samp[1];
    red[4][t] = samp[2]; red[5][t] = samp[3];
    __syncthreads();

    for (int off = 128; off > 0; off >>= 1) {
        if (t < off) {
            #pragma unroll
            for (int k = 0; k < 6; k++) red[k][t] += red[k][t + off];
        }
        __syncthreads();
    }

    if (t == 0) {
        out[0] = red[0][0] / red[1][0];  // ce_loss (masked mean)

        float dl[NDOM];
        int sc[NDOM];
        #pragma unroll
        for (int d = 0; d < NDOM; d++) { dl[d] = 0.0f; sc[d] = 0; }
        for (int b = 0; b < B; b++) {
            int d = domain_idxs[b];
            dl[d] += red[2 + b][0];
            sc[d] += 1;
        }
        #pragma unroll
        for (int d = 0; d < NDOM; d++) {
            float denom = (float)sc[d] * (float)S;
            out[1 + d]       = (denom > 0.0f) ? (dl[d] / denom) : 0.0f;
            out[1 + NDOM + d] = (float)sc[d];
        }
    }
}

extern "C" void kernel_launch(void* const* d_in, const int* in_sizes, int n_in,
                              void* d_out, int out_size, void* d_ws, size_t ws_size,
                              hipStream_t stream) {
    const float* logits     = (const float*)d_in[0];
    const int* labels       = (const int*)d_in[1];
    const int* mask         = (const int*)d_in[2];
    const int* domain_idxs  = (const int*)d_in[3];
    float* out              = (float*)d_out;

    const int T = in_sizes[1];                 // B*S = 8192
    const int V = (int)(in_sizes[0] / (size_t)T ? in_sizes[0] / T : 32000); // 32000
    const int B = in_sizes[3];                 // 4
    const int S = T / B;                       // 2048

    float* per_token_loss = (float*)d_ws;      // T floats = 32 KiB

    ce_per_token_kernel<<<T, 256, 0, stream>>>(logits, labels, per_token_loss, V);
    ce_finalize_kernel<<<1, 256, 0, stream>>>(per_token_loss, mask, domain_idxs,
                                              out, T, B, S);
}

// Round 2
// 1254.682 us; speedup vs baseline: 1.0376x; 1.0376x over previous
//
#include <hip/hip_runtime.h>
#include <hip/hip_bf16.h>
#include <math.h>

// CrossEntropyWithPerDomainLoss on MI355X (gfx950)
// B=4, S=2048, V=32000, D=8. Memory-bound: single pass over 1.048 GB of logits.
// R2: 4-way ILP online softmax (4 independent (m,s) chains, 4 loads in flight
// per wave) to convert the latency-bound loop into a bandwidth-bound one.

#define NDOM 8

typedef float v4f __attribute__((ext_vector_type(4)));
typedef int   v4i __attribute__((ext_vector_type(4)));

// ---------------- Kernel 1: per-token online-softmax CE loss ----------------
__global__ __launch_bounds__(256) void ce_per_token_kernel(
    const float* __restrict__ logits,   // [T, V]
    const int* __restrict__ labels,     // [T]
    float* __restrict__ per_token_loss, // [T] (workspace)
    int V)                              // vocab, multiple of 4
{
    const int token = blockIdx.x;
    const int t = threadIdx.x;
    const v4f* row = reinterpret_cast<const v4f*>(logits + (size_t)token * (size_t)V);
    const int V4 = V >> 2;
    const float L2E = 1.4426950408889634f;  // log2(e)
    const float LN2 = 0.6931471805599453f;

    // 4 independent online-softmax accumulators (breaks the serial exp chain,
    // lets 4 loads be outstanding per wave).
    float m[4]  = {-INFINITY, -INFINITY, -INFINITY, -INFINITY};
    float mL[4] = {0.f, 0.f, 0.f, 0.f};  // m * log2(e), refreshed on max update
    float s[4]  = {0.f, 0.f, 0.f, 0.f};  // sum of e^(x - m)

    auto upd = [&](int k, v4f v) {
        float m4 = fmaxf(fmaxf(v.x, v.y), fmaxf(v.z, v.w));
        if (m4 > m[k]) {                       // rare after warm-up
            s[k] *= exp2f((m[k] - m4) * L2E);  // exp2(-inf)=0 on first iter, s==0 anyway
            m[k] = m4;
            mL[k] = m4 * L2E;
        }
        // e^(x - m) == 2^(x*log2e - m*log2e), one FMA + native v_exp_f32 each
        s[k] += exp2f(fmaf(v.x, L2E, -mL[k])) + exp2f(fmaf(v.y, L2E, -mL[k]))
              + exp2f(fmaf(v.z, L2E, -mL[k])) + exp2f(fmaf(v.w, L2E, -mL[k]));
    };

    int j = t;
    for (; j + 768 < V4; j += 1024) {
        // issue all 4 loads before any compute -> 4 outstanding per wave
        v4f v0 = __builtin_nontemporal_load(row + j);
        v4f v1 = __builtin_nontemporal_load(row + j + 256);
        v4f v2 = __builtin_nontemporal_load(row + j + 512);
        v4f v3 = __builtin_nontemporal_load(row + j + 768);
        upd(0, v0); upd(1, v1); upd(2, v2); upd(3, v3);
    }
    for (; j < V4; j += 256) {  // tail (V4=8000: up to 4 extra chunks on chain 0)
        v4f v = __builtin_nontemporal_load(row + j);
        upd(0, v);
    }

    // merge the 4 per-thread accumulators
    float M = m[0], S = s[0];
    #pragma unroll
    for (int k = 1; k < 4; k++) {
        float mn = fmaxf(M, m[k]);
        S = S * exp2f((M - mn) * L2E) + s[k] * exp2f((m[k] - mn) * L2E);
        M = mn;
    }

    // 64-lane butterfly reduce of the (M, S) pair
    #pragma unroll
    for (int off = 1; off < 64; off <<= 1) {
        float mo = __shfl_xor(M, off, 64);
        float so = __shfl_xor(S, off, 64);
        float mn = fmaxf(M, mo);
        S = S * exp2f((M - mn) * L2E) + so * exp2f((mo - mn) * L2E);
        M = mn;
    }

    // combine the 4 waves via LDS
    __shared__ float sm[4];
    __shared__ float ss[4];
    const int wave = t >> 6;
    if ((t & 63) == 0) { sm[wave] = M; ss[wave] = S; }
    __syncthreads();

    if (t == 0) {
        float Mf = fmaxf(fmaxf(sm[0], sm[1]), fmaxf(sm[2], sm[3]));
        float Sf = ss[0] * exp2f((sm[0] - Mf) * L2E) + ss[1] * exp2f((sm[1] - Mf) * L2E)
                 + ss[2] * exp2f((sm[2] - Mf) * L2E) + ss[3] * exp2f((sm[3] - Mf) * L2E);
        int lab = labels[token];
        float x = logits[(size_t)token * (size_t)V + (size_t)lab];
        per_token_loss[token] = Mf + log2f(Sf) * LN2 - x;  // lse - logit[label]
    }
}

// ---------------- Kernel 2: reductions + per-domain finalize ----------------
// Single 256-thread block, vectorized. T = 8192 floats — negligible cost.
__global__ __launch_bounds__(256) void ce_finalize_kernel(
    const float* __restrict__ per_token_loss, // [T]
    const int* __restrict__ mask,             // [T] (bool as int32)
    const int* __restrict__ domain_idxs,      // [B]
    float* __restrict__ out,                  // [1 + NDOM + NDOM]
    int T, int B, int S)
{
    const int t = threadIdx.x;
    const v4f* pl4 = reinterpret_cast<const v4f*>(per_token_loss);
    const v4i* mk4 = reinterpret_cast<const v4i*>(mask);
    const int T4 = T >> 2;
    const int S4 = S >> 2;

    float tot = 0.0f, cnt = 0.0f;
    float samp[4] = {0.f, 0.f, 0.f, 0.f};  // B == 4

    for (int i = t; i < T4; i += 256) {   // 8 iterations
        v4f l = pl4[i];
        v4i mk = mk4[i];
        tot += (mk.x ? l.x : 0.f) + (mk.y ? l.y : 0.f)
             + (mk.z ? l.z : 0.f) + (mk.w ? l.w : 0.f);
        cnt += (mk.x ? 1.f : 0.f) + (mk.y ? 1.f : 0.f)
             + (mk.z ? 1.f : 0.f) + (mk.w ? 1.f : 0.f);
        samp[i / S4] += l.x + l.y + l.z + l.w;  // per-sample sums are UNMASKED
    }

    __shared__ float red[6][256];
    red[0][t] = tot;     red[1][t] = cnt;
    red[2][t] = samp[0]; red[3][t] = samp[1];
    red[4][t] = samp[2]; red[5][t] = samp[3];
    __syncthreads();

    for (int off = 128; off > 0; off >>= 1) {
        if (t < off) {
            #pragma unroll
            for (int k = 0; k < 6; k++) red[k][t] += red[k][t + off];
        }
        __syncthreads();
    }

    if (t == 0) {
        out[0] = red[0][0] / red[1][0];  // ce_loss (masked mean)

        float dl[NDOM];
        int sc[NDOM];
        #pragma unroll
        for (int d = 0; d < NDOM; d++) { dl[d] = 0.0f; sc[d] = 0; }
        for (int b = 0; b < B; b++) {
            int d = domain_idxs[b];
            dl[d] += red[2 + b][0];
            sc[d] += 1;
        }
        #pragma unroll
        for (int d = 0; d < NDOM; d++) {
            float denom = (float)sc[d] * (float)S;
            out[1 + d]        = (denom > 0.0f) ? (dl[d] / denom) : 0.0f;
            out[1 + NDOM + d] = (float)sc[d];
        }
    }
}

extern "C" void kernel_launch(void* const* d_in, const int* in_sizes, int n_in,
                              void* d_out, int out_size, void* d_ws, size_t ws_size,
                              hipStream_t stream) {
    const float* logits     = (const float*)d_in[0];
    const int* labels       = (const int*)d_in[1];
    const int* mask         = (const int*)d_in[2];
    const int* domain_idxs  = (const int*)d_in[3];
    float* out              = (float*)d_out;

    const int T = in_sizes[1];                 // B*S = 8192
    const int V = in_sizes[0] / T;             // 32000
    const int B = in_sizes[3];                 // 4
    const int S = T / B;                       // 2048

    float* per_token_loss = (float*)d_ws;      // T floats = 32 KiB

    ce_per_token_kernel<<<T, 256, 0, stream>>>(logits, labels, per_token_loss, V);
    ce_finalize_kernel<<<1, 256, 0, stream>>>(per_token_loss, mask, domain_idxs,
                                              out, T, B, S);
}